// Round 13
// baseline (230.688 us; speedup 1.0000x reference)
//
#include <hip/hip_runtime.h>
#include <hip/hip_fp16.h>
#include <math.h>

#define N_NODES 100000
#define N_EDGES 6400000
#define NF 128
#define NH 16
#define NB 128                          // nodes per bucket
#define KB 782                          // ceil(100000/128)
#define CAP 9216                        // static bucket capacity (mean 8192, sd ~90)

#define PT_THREADS 512
#define PT_EPT 16
#define PT_TILE (PT_THREADS * PT_EPT)   // 8192 edges per block
#define PT_BLOCKS ((N_EDGES + PT_TILE - 1) / PT_TILE)  // 782
#define PT_WAVES (PT_THREADS / 64)      // 8

// ---------------- single-pass partition: LDS multisplit + coalesced burst run writes ----------------
// 512-thread blocks, 3/CU (LDS-limited): 782 blocks execute in ~1.02 rounds (was 1.53 at 1024).
// Scan over KB buckets: pair-per-thread wave-shuffle scan, 3 block barriers total.
__global__ __launch_bounds__(PT_THREADS) void k_part(const int* __restrict__ src, const int* __restrict__ dst,
                                                     int* __restrict__ bcur, unsigned* __restrict__ part) {
    __shared__ int lcnt[KB];            // per-bucket count in this tile
    __shared__ int lbase[KB];           // global write base (absolute)
    __shared__ int cur[KB];             // LDS scatter cursors
    __shared__ int wsum[PT_WAVES];
    __shared__ int woff[PT_WAVES];
    __shared__ unsigned lsrt[PT_TILE];  // 32 KB tile-sorted packed edges
    int t = threadIdx.x;
    int e0 = blockIdx.x * PT_TILE;
    int d_reg[PT_EPT];

    for (int i = t; i < KB; i += PT_THREADS) lcnt[i] = 0;
    __syncthreads();
    // pass 1: histogram (cache dst in regs)
    #pragma unroll
    for (int r = 0; r < PT_EPT; r++) {
        int i = e0 + r * PT_THREADS + t;
        if (i < N_EDGES) {
            d_reg[r] = dst[i];
            atomicAdd(&lcnt[d_reg[r] >> 7], 1);
        } else d_reg[r] = -1;
    }
    __syncthreads();
    // pair-per-thread wave-shuffle exclusive scan: thread t owns buckets 2t, 2t+1
    int lane_ = t & 63, wv_ = t >> 6;
    int b0 = 2 * t, b1 = 2 * t + 1;
    int c0 = (b0 < KB) ? lcnt[b0] : 0;
    int c1 = (b1 < KB) ? lcnt[b1] : 0;
    int p = c0 + c1;
    int inc = p;
    #pragma unroll
    for (int d = 1; d < 64; d <<= 1) {
        int u = __shfl_up(inc, d, 64);
        if (lane_ >= d) inc += u;
    }
    if (lane_ == 63) wsum[wv_] = inc;
    __syncthreads();
    if (t < PT_WAVES) {
        int s = 0;
        for (int k = 0; k < t; k++) s += wsum[k];
        woff[t] = s;
    }
    __syncthreads();
    int exc = inc - p + woff[wv_];      // exclusive over pairs
    if (b0 < KB) cur[b0] = exc;
    if (b1 < KB) cur[b1] = exc + c0;
    // reserve global run space: one atomic per (block,bucket)
    for (int b = t; b < KB; b += PT_THREADS) {
        int c = lcnt[b];
        lbase[b] = b * CAP + (c ? atomicAdd(&bcur[b], c) : 0);
    }
    __syncthreads();
    // pass 2: rank-scatter packed edges into LDS (reload src)
    #pragma unroll
    for (int r = 0; r < PT_EPT; r++) {
        int d = d_reg[r];
        if (d >= 0) {
            int i = e0 + r * PT_THREADS + t;
            int pp = atomicAdd(&cur[d >> 7], 1);
            lsrt[pp] = ((unsigned)src[i] << 7) | (unsigned)(d & (NB - 1));
        }
    }
    __syncthreads();
    // pass 3: burst writeback, one wave per bucket-run, lanes coalesced
    int wv = t >> 6, ln = t & 63;
    for (int b = wv; b < KB; b += PT_WAVES) {
        int c = lcnt[b];
        if (!c) continue;
        int gb = lbase[b];
        int lb = cur[b] - c;                    // run start in LDS
        int lim = (b + 1) * CAP - gb;           // overflow clamp (statistically never)
        int cc = c < lim ? c : lim;
        for (int k = ln; k < cc; k += 64) part[gb + k] = lsrt[lb + k];
    }
}

// ---------------- per-bucket LDS sort -> node-sorted src list (in place) + CSR + dinv ----------------
__global__ __launch_bounds__(512) void k_sort(unsigned* __restrict__ part, const int* __restrict__ bcur,
                                              int* __restrict__ off, int* __restrict__ off_end,
                                              float* __restrict__ dinv) {
    __shared__ int deg[NB];
    __shared__ int sc[NB];
    __shared__ int offl[NB];
    __shared__ int cur[NB];
    __shared__ int lsort[CAP];  // 36 KB
    int b = blockIdx.x, t = threadIdx.x;
    int e0 = b * CAP;
    int cnt = bcur[b];
    if (cnt > CAP) cnt = CAP;
    for (int i = t; i < NB; i += 512) deg[i] = 0;
    __syncthreads();
    // local degree histogram
    for (int i = t; i < cnt; i += 512) atomicAdd(&deg[part[e0 + i] & (NB - 1)], 1);
    __syncthreads();
    // exclusive scan over 128 local nodes
    if (t < NB) sc[t] = deg[t];
    __syncthreads();
    for (int d = 1; d < NB; d <<= 1) {
        int add = (t < NB && t >= d) ? sc[t - d] : 0;
        __syncthreads();
        if (t < NB) sc[t] += add;
        __syncthreads();
    }
    if (t < NB) { int ex = sc[t] - deg[t]; offl[t] = ex; cur[t] = ex; }
    __syncthreads();
    // scatter srcs into LDS at final rank
    for (int i = t; i < cnt; i += 512) {
        unsigned u = part[e0 + i];
        int r = atomicAdd(&cur[u & (NB - 1)], 1);
        lsort[r] = (int)(u >> 7);
    }
    __syncthreads();
    // coalesced writeback (in place)
    for (int i = t; i < cnt; i += 512) part[e0 + i] = (unsigned)lsort[i];
    // node-level CSR + dinv
    if (t < NB) {
        int n = b * NB + t;
        if (n < N_NODES) {
            off[n] = e0 + offl[t];
            off_end[n] = e0 + offl[t] + deg[t];
            dinv[n] = rsqrtf((float)(deg[t] + 1));  // +1 self loop
        }
    }
}

// ---------------- g1 = fp16( dinv * (x @ W1) ) ----------------
__global__ __launch_bounds__(256) void k_gemm1(const float* __restrict__ x, const float* __restrict__ W1,
                                               const float* __restrict__ dinv, __half* __restrict__ g1) {
    __shared__ float Ws[NF * NH];  // 8 KB
    for (int i = threadIdx.x; i < NF * NH; i += 256) Ws[i] = W1[i];
    __syncthreads();
    int gid = blockIdx.x * 256 + threadIdx.x;
    int n = gid >> 4, j = gid & 15;
    if (n >= N_NODES) return;
    const float4* xr = (const float4*)(x + (size_t)n * NF);
    float acc = 0.f;
    #pragma unroll
    for (int k4 = 0; k4 < NF / 4; k4++) {
        float4 v = xr[k4];
        acc += v.x * Ws[(k4 * 4 + 0) * NH + j];
        acc += v.y * Ws[(k4 * 4 + 1) * NH + j];
        acc += v.z * Ws[(k4 * 4 + 2) * NH + j];
        acc += v.w * Ws[(k4 * 4 + 3) * NH + j];
    }
    g1[(size_t)n * NH + j] = __float2half(dinv[n] * acc);
}

// ---- pull aggregate (R10 champion config): 1 wave/node, 2 lanes/edge-halfrow,
// 128 edges/iter (4 slots/lane), f16 packed accumulate, bpermute shuffle tree.
// LAYER1: relu + W2 fused (fp16 out, dinv folded).  LAYER2: sigmoid, f32 out.
__device__ __forceinline__ __half2 shx(__half2 x, int m) {
    union { __half2 h; int i; } u;
    u.h = x;
    u.i = __shfl_xor(u.i, m, 64);
    return u.h;
}

template <int LAYER>
__global__ __launch_bounds__(256) void k_agg(const __half* __restrict__ g, const int* __restrict__ off,
                                             const int* __restrict__ off_end,
                                             const unsigned* __restrict__ sorted,
                                             const float* __restrict__ dinv,
                                             const float* __restrict__ bias, const float* __restrict__ W2,
                                             void* __restrict__ outp) {
    __shared__ __align__(16) unsigned redu[4][8];   // [wave][c*4 + word]: raw f16-pair sums
    __shared__ float redf[4][NH];                   // [wave]: relu row (layer 1)
    __shared__ __align__(16) float W2T[16 * 20];    // W2 transposed, +4 pad
    int t = threadIdx.x;
    if (LAYER == 1) {
        int j = t >> 4, k = t & 15;
        W2T[j * 20 + k] = W2[k * 16 + j];           // W2T[j][k] = W2[k][j]
        __syncthreads();
    }
    int w = t >> 6, lane = t & 63;
    int n = blockIdx.x * 4 + w;                     // grid exact: 25000*4 = 100000
    int slot = lane & 31, c = lane >> 5;            // edge slot, 16B half-row selector
    int o0 = off[n], o1 = off_end[n];
    const char* gbase = (const char*)g + (c << 4);

    // hoisted: self row + dinv (overlap with gather loop)
    int j = lane & 15;
    float dn = dinv[n];
    float selfj = __half2float(g[(size_t)n * NH + j]);

    union HV { uint4 q; __half2 h[4]; };
    __half2 a0 = __half2(0.f, 0.f), a1 = a0, a2 = a0, a3 = a0;
    for (int eb = o0; eb < o1; eb += 128) {
        int e1 = eb + slot, e2 = e1 + 32, e3 = e1 + 64, e4 = e1 + 96;
        HV v1, v2, v3, v4;
        v1.q = make_uint4(0u, 0u, 0u, 0u);
        v2.q = make_uint4(0u, 0u, 0u, 0u);
        v3.q = make_uint4(0u, 0u, 0u, 0u);
        v4.q = make_uint4(0u, 0u, 0u, 0u);
        if (e1 < o1) {
            unsigned s = sorted[e1];
            v1.q = *(const uint4*)(gbase + ((size_t)s << 5));
        }
        if (e2 < o1) {
            unsigned s = sorted[e2];
            v2.q = *(const uint4*)(gbase + ((size_t)s << 5));
        }
        if (e3 < o1) {
            unsigned s = sorted[e3];
            v3.q = *(const uint4*)(gbase + ((size_t)s << 5));
        }
        if (e4 < o1) {
            unsigned s = sorted[e4];
            v4.q = *(const uint4*)(gbase + ((size_t)s << 5));
        }
        a0 = __hadd2(a0, __hadd2(__hadd2(v1.h[0], v2.h[0]), __hadd2(v3.h[0], v4.h[0])));
        a1 = __hadd2(a1, __hadd2(__hadd2(v1.h[1], v2.h[1]), __hadd2(v3.h[1], v4.h[1])));
        a2 = __hadd2(a2, __hadd2(__hadd2(v1.h[2], v2.h[2]), __hadd2(v3.h[2], v4.h[2])));
        a3 = __hadd2(a3, __hadd2(__hadd2(v1.h[3], v2.h[3]), __hadd2(v3.h[3], v4.h[3])));
    }
    // 5-stage tree over each 32-lane half (xor masks < 32 keep halves separate)
    #pragma unroll
    for (int m = 1; m <= 16; m <<= 1) {
        a0 = __hadd2(a0, shx(a0, m));
        a1 = __hadd2(a1, shx(a1, m));
        a2 = __hadd2(a2, shx(a2, m));
        a3 = __hadd2(a3, shx(a3, m));
    }
    // lanes 0 and 32 publish raw words (one ds_write_b128 each)
    if (slot == 0) {
        union { uint4 q; __half2 h[4]; } p;
        p.h[0] = a0; p.h[1] = a1; p.h[2] = a2; p.h[3] = a3;
        *(uint4*)&redu[w][c * 4] = p.q;
    }
    // feature j -> half j>>3, word (j&7)>>1, f16 sel j&1   (same-wave LDS RAW: in-order)
    union { unsigned u; __half2 h; } pick;
    pick.u = redu[w][((j >> 3) << 2) + ((j & 7) >> 1)];
    float sumj = __half2float((j & 1) ? __high2half(pick.h) : __low2half(pick.h));
    if (LAYER == 1) {
        if (lane < NH) {
            redf[w][j] = fmaxf(fmaf(dn, sumj + selfj, bias[j]), 0.f);
            float4 r0 = *(const float4*)&redf[w][0];
            float4 r1 = *(const float4*)&redf[w][4];
            float4 r2 = *(const float4*)&redf[w][8];
            float4 r3 = *(const float4*)&redf[w][12];
            const float* wr = &W2T[j * 20];
            float4 w0 = *(const float4*)&wr[0];
            float4 w1 = *(const float4*)&wr[4];
            float4 w2 = *(const float4*)&wr[8];
            float4 w3 = *(const float4*)&wr[12];
            float h = r0.x * w0.x + r0.y * w0.y + r0.z * w0.z + r0.w * w0.w
                    + r1.x * w1.x + r1.y * w1.y + r1.z * w1.z + r1.w * w1.w
                    + r2.x * w2.x + r2.y * w2.y + r2.z * w2.z + r2.w * w2.w
                    + r3.x * w3.x + r3.y * w3.y + r3.z * w3.z + r3.w * w3.w;
            ((__half*)outp)[(size_t)n * NH + j] = __float2half(dn * h);
        }
    } else {
        if (lane < NH) {
            float z = fmaf(dn, sumj + selfj, bias[j]);
            ((float*)outp)[(size_t)n * NH + j] = 1.f / (1.f + __expf(-z));
        }
    }
}

extern "C" void kernel_launch(void* const* d_in, const int* in_sizes, int n_in,
                              void* d_out, int out_size, void* d_ws, size_t ws_size,
                              hipStream_t stream) {
    const float* x  = (const float*)d_in[0];
    const int* eidx = (const int*)d_in[1];
    const float* W1 = (const float*)d_in[2];
    const float* b1 = (const float*)d_in[3];
    const float* W2 = (const float*)d_in[4];
    const float* b2 = (const float*)d_in[5];
    const int* src = eidx;
    const int* dst = eidx + N_EDGES;
    float* out = (float*)d_out;

    char* ws = (char*)d_ws;
    size_t o = 0;
    auto alloc = [&](size_t bytes) { size_t r = o; o = (o + bytes + 255) & ~(size_t)255; return r; };
    int*      bcur    = (int*)     (ws + alloc(sizeof(int) * KB));
    unsigned* part    = (unsigned*)(ws + alloc(sizeof(unsigned) * ((size_t)KB * CAP + 512)));  // +pad
    int*      off     = (int*)     (ws + alloc(sizeof(int) * N_NODES));
    int*      off_end = (int*)     (ws + alloc(sizeof(int) * N_NODES));
    float*    dinv    = (float*)   (ws + alloc(sizeof(float) * N_NODES));
    __half*   g1      = (__half*)  (ws + alloc(sizeof(__half) * N_NODES * NH));
    __half*   g2      = (__half*)  (ws + alloc(sizeof(__half) * N_NODES * NH));
    (void)ws_size; (void)n_in; (void)in_sizes; (void)out_size;

    hipMemsetAsync(bcur, 0, sizeof(int) * KB, stream);

    k_part<<<PT_BLOCKS, PT_THREADS, 0, stream>>>(src, dst, bcur, part);
    k_sort<<<KB, 512, 0, stream>>>(part, bcur, off, off_end, dinv);

    k_gemm1<<<(N_NODES * NH + 255) / 256, 256, 0, stream>>>(x, W1, dinv, g1);

    k_agg<1><<<N_NODES / 4, 256, 0, stream>>>(g1, off, off_end, part, dinv, b1, W2, g2);
    k_agg<2><<<N_NODES / 4, 256, 0, stream>>>(g2, off, off_end, part, dinv, b2, nullptr, out);
}

// Round 14
// 189.134 us; speedup vs baseline: 1.2197x; 1.2197x over previous
//
#include <hip/hip_runtime.h>
#include <hip/hip_fp16.h>
#include <math.h>

#define N_NODES 100000
#define N_EDGES 6400000
#define NF 128
#define NH 16
#define NB 128                          // nodes per bucket
#define KB 782                          // ceil(100000/128)
#define CAP 9216                        // static bucket capacity (mean 8192, sd ~90)

#define PT_THREADS 1024
#define PT_EPT 16
#define PT_TILE (PT_THREADS * PT_EPT)   // 16384 edges per block (long runs -> low write amp)
#define PT_BLOCKS ((N_EDGES + PT_TILE - 1) / PT_TILE)  // 391
#define PT_WAVES (PT_THREADS / 64)      // 16

// ---------------- single-pass partition: LDS multisplit + coalesced burst run writes ----------------
// R11-proven config: 1024 threads, 16K tile, wave-shuffle scan (3 barriers).
// NOTE (R13 lesson): smaller tiles shorten bucket-runs -> partial-line write amplification dominates.
__global__ __launch_bounds__(PT_THREADS) void k_part(const int* __restrict__ src, const int* __restrict__ dst,
                                                     int* __restrict__ bcur, unsigned* __restrict__ part) {
    __shared__ int lcnt[KB];            // per-bucket count in this tile
    __shared__ int lbase[KB];           // global write base (absolute)
    __shared__ int cur[KB];             // LDS scatter cursors
    __shared__ int wsum[PT_WAVES];
    __shared__ int woff[PT_WAVES];
    __shared__ unsigned lsrt[PT_TILE];  // 64 KB tile-sorted packed edges
    int t = threadIdx.x;
    int e0 = blockIdx.x * PT_TILE;
    int d_reg[PT_EPT];

    for (int i = t; i < KB; i += PT_THREADS) lcnt[i] = 0;
    __syncthreads();
    // pass 1: histogram (cache dst in regs)
    #pragma unroll
    for (int r = 0; r < PT_EPT; r++) {
        int i = e0 + r * PT_THREADS + t;
        if (i < N_EDGES) {
            d_reg[r] = dst[i];
            atomicAdd(&lcnt[d_reg[r] >> 7], 1);
        } else d_reg[r] = -1;
    }
    __syncthreads();
    // wave-shuffle exclusive scan of lcnt[0..KB)
    int lane_ = t & 63, wv_ = t >> 6;
    int v = (t < KB) ? lcnt[t] : 0;
    int inc = v;
    #pragma unroll
    for (int d = 1; d < 64; d <<= 1) {
        int u = __shfl_up(inc, d, 64);
        if (lane_ >= d) inc += u;
    }
    if (lane_ == 63) wsum[wv_] = inc;
    __syncthreads();
    if (t < PT_WAVES) {
        int s = 0;
        for (int k = 0; k < t; k++) s += wsum[k];
        woff[t] = s;
    }
    __syncthreads();
    if (t < KB) cur[t] = inc - v + woff[wv_];   // exclusive scan result
    // reserve global run space: one atomic per (block,bucket)
    for (int b = t; b < KB; b += PT_THREADS) {
        int c = lcnt[b];
        lbase[b] = b * CAP + (c ? atomicAdd(&bcur[b], c) : 0);
    }
    __syncthreads();
    // pass 2: rank-scatter packed edges into LDS (reload src)
    #pragma unroll
    for (int r = 0; r < PT_EPT; r++) {
        int d = d_reg[r];
        if (d >= 0) {
            int i = e0 + r * PT_THREADS + t;
            int p = atomicAdd(&cur[d >> 7], 1);
            lsrt[p] = ((unsigned)src[i] << 7) | (unsigned)(d & (NB - 1));
        }
    }
    __syncthreads();
    // pass 3: burst writeback, one wave per bucket-run, lanes coalesced
    int wv = t >> 6, ln = t & 63;
    for (int b = wv; b < KB; b += PT_WAVES) {
        int c = lcnt[b];
        if (!c) continue;
        int gb = lbase[b];
        int lb = cur[b] - c;                    // run start in LDS
        int lim = (b + 1) * CAP - gb;           // overflow clamp (statistically never)
        int cc = c < lim ? c : lim;
        for (int k = ln; k < cc; k += 64) part[gb + k] = lsrt[lb + k];
    }
}

// ---------------- per-bucket LDS sort -> node-sorted src list (in place) + CSR + dinv ----------------
__global__ __launch_bounds__(512) void k_sort(unsigned* __restrict__ part, const int* __restrict__ bcur,
                                              int* __restrict__ off, int* __restrict__ off_end,
                                              float* __restrict__ dinv) {
    __shared__ int deg[NB];
    __shared__ int sc[NB];
    __shared__ int offl[NB];
    __shared__ int cur[NB];
    __shared__ int lsort[CAP];  // 36 KB
    int b = blockIdx.x, t = threadIdx.x;
    int e0 = b * CAP;
    int cnt = bcur[b];
    if (cnt > CAP) cnt = CAP;
    for (int i = t; i < NB; i += 512) deg[i] = 0;
    __syncthreads();
    // local degree histogram
    for (int i = t; i < cnt; i += 512) atomicAdd(&deg[part[e0 + i] & (NB - 1)], 1);
    __syncthreads();
    // exclusive scan over 128 local nodes
    if (t < NB) sc[t] = deg[t];
    __syncthreads();
    for (int d = 1; d < NB; d <<= 1) {
        int add = (t < NB && t >= d) ? sc[t - d] : 0;
        __syncthreads();
        if (t < NB) sc[t] += add;
        __syncthreads();
    }
    if (t < NB) { int ex = sc[t] - deg[t]; offl[t] = ex; cur[t] = ex; }
    __syncthreads();
    // scatter srcs into LDS at final rank
    for (int i = t; i < cnt; i += 512) {
        unsigned u = part[e0 + i];
        int r = atomicAdd(&cur[u & (NB - 1)], 1);
        lsort[r] = (int)(u >> 7);
    }
    __syncthreads();
    // coalesced writeback (in place)
    for (int i = t; i < cnt; i += 512) part[e0 + i] = (unsigned)lsort[i];
    // node-level CSR + dinv
    if (t < NB) {
        int n = b * NB + t;
        if (n < N_NODES) {
            off[n] = e0 + offl[t];
            off_end[n] = e0 + offl[t] + deg[t];
            dinv[n] = rsqrtf((float)(deg[t] + 1));  // +1 self loop
        }
    }
}

// ---------------- g1 = fp16( dinv * (x @ W1) ) ----------------
__global__ __launch_bounds__(256) void k_gemm1(const float* __restrict__ x, const float* __restrict__ W1,
                                               const float* __restrict__ dinv, __half* __restrict__ g1) {
    __shared__ float Ws[NF * NH];  // 8 KB
    for (int i = threadIdx.x; i < NF * NH; i += 256) Ws[i] = W1[i];
    __syncthreads();
    int gid = blockIdx.x * 256 + threadIdx.x;
    int n = gid >> 4, j = gid & 15;
    if (n >= N_NODES) return;
    const float4* xr = (const float4*)(x + (size_t)n * NF);
    float acc = 0.f;
    #pragma unroll
    for (int k4 = 0; k4 < NF / 4; k4++) {
        float4 v = xr[k4];
        acc += v.x * Ws[(k4 * 4 + 0) * NH + j];
        acc += v.y * Ws[(k4 * 4 + 1) * NH + j];
        acc += v.z * Ws[(k4 * 4 + 2) * NH + j];
        acc += v.w * Ws[(k4 * 4 + 3) * NH + j];
    }
    g1[(size_t)n * NH + j] = __float2half(dinv[n] * acc);
}

// ---- pull aggregate (R10 champion): 1 wave/node, 2 lanes/edge-halfrow, 128 edges/iter
// (4 slots/lane), f16 packed accumulate, bpermute shuffle tree, plain conditional loads.
// LAYER1: relu + W2 fused (fp16 out, dinv folded).  LAYER2: sigmoid, f32 out.
__device__ __forceinline__ __half2 shx(__half2 x, int m) {
    union { __half2 h; int i; } u;
    u.h = x;
    u.i = __shfl_xor(u.i, m, 64);
    return u.h;
}

template <int LAYER>
__global__ __launch_bounds__(256) void k_agg(const __half* __restrict__ g, const int* __restrict__ off,
                                             const int* __restrict__ off_end,
                                             const unsigned* __restrict__ sorted,
                                             const float* __restrict__ dinv,
                                             const float* __restrict__ bias, const float* __restrict__ W2,
                                             void* __restrict__ outp) {
    __shared__ __align__(16) unsigned redu[4][8];   // [wave][c*4 + word]: raw f16-pair sums
    __shared__ float redf[4][NH];                   // [wave]: relu row (layer 1)
    __shared__ __align__(16) float W2T[16 * 20];    // W2 transposed, +4 pad
    int t = threadIdx.x;
    if (LAYER == 1) {
        int j = t >> 4, k = t & 15;
        W2T[j * 20 + k] = W2[k * 16 + j];           // W2T[j][k] = W2[k][j]
        __syncthreads();
    }
    int w = t >> 6, lane = t & 63;
    int n = blockIdx.x * 4 + w;                     // grid exact: 25000*4 = 100000
    int slot = lane & 31, c = lane >> 5;            // edge slot, 16B half-row selector
    int o0 = off[n], o1 = off_end[n];
    const char* gbase = (const char*)g + (c << 4);

    // hoisted: self row + dinv (overlap with gather loop)
    int j = lane & 15;
    float dn = dinv[n];
    float selfj = __half2float(g[(size_t)n * NH + j]);

    union HV { uint4 q; __half2 h[4]; };
    __half2 a0 = __half2(0.f, 0.f), a1 = a0, a2 = a0, a3 = a0;
    for (int eb = o0; eb < o1; eb += 128) {
        int e1 = eb + slot, e2 = e1 + 32, e3 = e1 + 64, e4 = e1 + 96;
        HV v1, v2, v3, v4;
        v1.q = make_uint4(0u, 0u, 0u, 0u);
        v2.q = make_uint4(0u, 0u, 0u, 0u);
        v3.q = make_uint4(0u, 0u, 0u, 0u);
        v4.q = make_uint4(0u, 0u, 0u, 0u);
        if (e1 < o1) {
            unsigned s = sorted[e1];
            v1.q = *(const uint4*)(gbase + ((size_t)s << 5));
        }
        if (e2 < o1) {
            unsigned s = sorted[e2];
            v2.q = *(const uint4*)(gbase + ((size_t)s << 5));
        }
        if (e3 < o1) {
            unsigned s = sorted[e3];
            v3.q = *(const uint4*)(gbase + ((size_t)s << 5));
        }
        if (e4 < o1) {
            unsigned s = sorted[e4];
            v4.q = *(const uint4*)(gbase + ((size_t)s << 5));
        }
        a0 = __hadd2(a0, __hadd2(__hadd2(v1.h[0], v2.h[0]), __hadd2(v3.h[0], v4.h[0])));
        a1 = __hadd2(a1, __hadd2(__hadd2(v1.h[1], v2.h[1]), __hadd2(v3.h[1], v4.h[1])));
        a2 = __hadd2(a2, __hadd2(__hadd2(v1.h[2], v2.h[2]), __hadd2(v3.h[2], v4.h[2])));
        a3 = __hadd2(a3, __hadd2(__hadd2(v1.h[3], v2.h[3]), __hadd2(v3.h[3], v4.h[3])));
    }
    // 5-stage tree over each 32-lane half (xor masks < 32 keep halves separate)
    #pragma unroll
    for (int m = 1; m <= 16; m <<= 1) {
        a0 = __hadd2(a0, shx(a0, m));
        a1 = __hadd2(a1, shx(a1, m));
        a2 = __hadd2(a2, shx(a2, m));
        a3 = __hadd2(a3, shx(a3, m));
    }
    // lanes 0 and 32 publish raw words (one ds_write_b128 each)
    if (slot == 0) {
        union { uint4 q; __half2 h[4]; } p;
        p.h[0] = a0; p.h[1] = a1; p.h[2] = a2; p.h[3] = a3;
        *(uint4*)&redu[w][c * 4] = p.q;
    }
    // feature j -> half j>>3, word (j&7)>>1, f16 sel j&1   (same-wave LDS RAW: in-order)
    union { unsigned u; __half2 h; } pick;
    pick.u = redu[w][((j >> 3) << 2) + ((j & 7) >> 1)];
    float sumj = __half2float((j & 1) ? __high2half(pick.h) : __low2half(pick.h));
    if (LAYER == 1) {
        if (lane < NH) {
            redf[w][j] = fmaxf(fmaf(dn, sumj + selfj, bias[j]), 0.f);
            float4 r0 = *(const float4*)&redf[w][0];
            float4 r1 = *(const float4*)&redf[w][4];
            float4 r2 = *(const float4*)&redf[w][8];
            float4 r3 = *(const float4*)&redf[w][12];
            const float* wr = &W2T[j * 20];
            float4 w0 = *(const float4*)&wr[0];
            float4 w1 = *(const float4*)&wr[4];
            float4 w2 = *(const float4*)&wr[8];
            float4 w3 = *(const float4*)&wr[12];
            float h = r0.x * w0.x + r0.y * w0.y + r0.z * w0.z + r0.w * w0.w
                    + r1.x * w1.x + r1.y * w1.y + r1.z * w1.z + r1.w * w1.w
                    + r2.x * w2.x + r2.y * w2.y + r2.z * w2.z + r2.w * w2.w
                    + r3.x * w3.x + r3.y * w3.y + r3.z * w3.z + r3.w * w3.w;
            ((__half*)outp)[(size_t)n * NH + j] = __float2half(dn * h);
        }
    } else {
        if (lane < NH) {
            float z = fmaf(dn, sumj + selfj, bias[j]);
            ((float*)outp)[(size_t)n * NH + j] = 1.f / (1.f + __expf(-z));
        }
    }
}

extern "C" void kernel_launch(void* const* d_in, const int* in_sizes, int n_in,
                              void* d_out, int out_size, void* d_ws, size_t ws_size,
                              hipStream_t stream) {
    const float* x  = (const float*)d_in[0];
    const int* eidx = (const int*)d_in[1];
    const float* W1 = (const float*)d_in[2];
    const float* b1 = (const float*)d_in[3];
    const float* W2 = (const float*)d_in[4];
    const float* b2 = (const float*)d_in[5];
    const int* src = eidx;
    const int* dst = eidx + N_EDGES;
    float* out = (float*)d_out;

    char* ws = (char*)d_ws;
    size_t o = 0;
    auto alloc = [&](size_t bytes) { size_t r = o; o = (o + bytes + 255) & ~(size_t)255; return r; };
    int*      bcur    = (int*)     (ws + alloc(sizeof(int) * KB));
    unsigned* part    = (unsigned*)(ws + alloc(sizeof(unsigned) * ((size_t)KB * CAP + 512)));  // +pad
    int*      off     = (int*)     (ws + alloc(sizeof(int) * N_NODES));
    int*      off_end = (int*)     (ws + alloc(sizeof(int) * N_NODES));
    float*    dinv    = (float*)   (ws + alloc(sizeof(float) * N_NODES));
    __half*   g1      = (__half*)  (ws + alloc(sizeof(__half) * N_NODES * NH));
    __half*   g2      = (__half*)  (ws + alloc(sizeof(__half) * N_NODES * NH));
    (void)ws_size; (void)n_in; (void)in_sizes; (void)out_size;

    hipMemsetAsync(bcur, 0, sizeof(int) * KB, stream);

    k_part<<<PT_BLOCKS, PT_THREADS, 0, stream>>>(src, dst, bcur, part);
    k_sort<<<KB, 512, 0, stream>>>(part, bcur, off, off_end, dinv);

    k_gemm1<<<(N_NODES * NH + 255) / 256, 256, 0, stream>>>(x, W1, dinv, g1);

    k_agg<1><<<N_NODES / 4, 256, 0, stream>>>(g1, off, off_end, part, dinv, b1, W2, g2);
    k_agg<2><<<N_NODES / 4, 256, 0, stream>>>(g2, off, off_end, part, dinv, b2, nullptr, out);
}

// Round 15
// 185.214 us; speedup vs baseline: 1.2455x; 1.0212x over previous
//
#include <hip/hip_runtime.h>
#include <hip/hip_fp16.h>
#include <math.h>

#define N_NODES 100000
#define N_EDGES 6400000
#define NF 128
#define NH 16
#define NB 128                          // nodes per bucket
#define KB 782                          // ceil(100000/128)
#define CAP 9216                        // static bucket capacity (mean 8192, sd ~90)

#define PT_THREADS 1024
#define PT_EPT 16
#define PT_TILE (PT_THREADS * PT_EPT)   // 16384 edges per block (long runs -> low write amp)
#define PT_BLOCKS ((N_EDGES + PT_TILE - 1) / PT_TILE)  // 391
#define PT_WAVES (PT_THREADS / 64)      // 16
#define PT_V4 (PT_EPT / 4)              // 4 dwordx4 loads per lane per pass

// ---------------- single-pass partition: LDS multisplit + coalesced burst run writes ----------------
// R11-proven structure (1024 threads, 16K tile, wave-shuffle scan, 3 barriers) with dwordx4
// edge loads: 32 scalar VMEM issues/lane -> 8.  Lane owns 4 consecutive edges per load; edge
// order within a bucket is irrelevant (rank-scatter + k_sort re-sort).
__global__ __launch_bounds__(PT_THREADS) void k_part(const int* __restrict__ src, const int* __restrict__ dst,
                                                     int* __restrict__ bcur, unsigned* __restrict__ part) {
    __shared__ int lcnt[KB];            // per-bucket count in this tile
    __shared__ int lbase[KB];           // global write base (absolute)
    __shared__ int cur[KB];             // LDS scatter cursors
    __shared__ int wsum[PT_WAVES];
    __shared__ int woff[PT_WAVES];
    __shared__ unsigned lsrt[PT_TILE];  // 64 KB tile-sorted packed edges
    int t = threadIdx.x;
    int e0 = blockIdx.x * PT_TILE;
    int d_reg[PT_EPT];

    for (int i = t; i < KB; i += PT_THREADS) lcnt[i] = 0;
    __syncthreads();
    // pass 1: histogram (dwordx4 dst loads, cache in regs)
    #pragma unroll
    for (int r = 0; r < PT_V4; r++) {
        int i = e0 + (r * PT_THREADS + t) * 4;
        if (i + 3 < N_EDGES) {
            int4 d4 = *(const int4*)(dst + i);
            d_reg[r * 4 + 0] = d4.x; d_reg[r * 4 + 1] = d4.y;
            d_reg[r * 4 + 2] = d4.z; d_reg[r * 4 + 3] = d4.w;
            atomicAdd(&lcnt[d4.x >> 7], 1);
            atomicAdd(&lcnt[d4.y >> 7], 1);
            atomicAdd(&lcnt[d4.z >> 7], 1);
            atomicAdd(&lcnt[d4.w >> 7], 1);
        } else {
            #pragma unroll
            for (int k = 0; k < 4; k++) {
                int ii = i + k;
                if (ii < N_EDGES) {
                    int d = dst[ii];
                    d_reg[r * 4 + k] = d;
                    atomicAdd(&lcnt[d >> 7], 1);
                } else d_reg[r * 4 + k] = -1;
            }
        }
    }
    __syncthreads();
    // wave-shuffle exclusive scan of lcnt[0..KB)
    int lane_ = t & 63, wv_ = t >> 6;
    int v = (t < KB) ? lcnt[t] : 0;
    int inc = v;
    #pragma unroll
    for (int d = 1; d < 64; d <<= 1) {
        int u = __shfl_up(inc, d, 64);
        if (lane_ >= d) inc += u;
    }
    if (lane_ == 63) wsum[wv_] = inc;
    __syncthreads();
    if (t < PT_WAVES) {
        int s = 0;
        for (int k = 0; k < t; k++) s += wsum[k];
        woff[t] = s;
    }
    __syncthreads();
    if (t < KB) cur[t] = inc - v + woff[wv_];   // exclusive scan result
    // reserve global run space: one atomic per (block,bucket)
    for (int b = t; b < KB; b += PT_THREADS) {
        int c = lcnt[b];
        lbase[b] = b * CAP + (c ? atomicAdd(&bcur[b], c) : 0);
    }
    __syncthreads();
    // pass 2: rank-scatter packed edges into LDS (dwordx4 src reload)
    #pragma unroll
    for (int r = 0; r < PT_V4; r++) {
        int i = e0 + (r * PT_THREADS + t) * 4;
        if (i + 3 < N_EDGES) {
            int4 s4 = *(const int4*)(src + i);
            int d0 = d_reg[r * 4 + 0], d1 = d_reg[r * 4 + 1];
            int d2 = d_reg[r * 4 + 2], d3 = d_reg[r * 4 + 3];
            int p0 = atomicAdd(&cur[d0 >> 7], 1);
            lsrt[p0] = ((unsigned)s4.x << 7) | (unsigned)(d0 & (NB - 1));
            int p1 = atomicAdd(&cur[d1 >> 7], 1);
            lsrt[p1] = ((unsigned)s4.y << 7) | (unsigned)(d1 & (NB - 1));
            int p2 = atomicAdd(&cur[d2 >> 7], 1);
            lsrt[p2] = ((unsigned)s4.z << 7) | (unsigned)(d2 & (NB - 1));
            int p3 = atomicAdd(&cur[d3 >> 7], 1);
            lsrt[p3] = ((unsigned)s4.w << 7) | (unsigned)(d3 & (NB - 1));
        } else {
            #pragma unroll
            for (int k = 0; k < 4; k++) {
                int d = d_reg[r * 4 + k];
                if (d >= 0) {
                    int ii = i + k;
                    int p = atomicAdd(&cur[d >> 7], 1);
                    lsrt[p] = ((unsigned)src[ii] << 7) | (unsigned)(d & (NB - 1));
                }
            }
        }
    }
    __syncthreads();
    // pass 3: burst writeback, one wave per bucket-run, lanes coalesced
    int wv = t >> 6, ln = t & 63;
    for (int b = wv; b < KB; b += PT_WAVES) {
        int c = lcnt[b];
        if (!c) continue;
        int gb = lbase[b];
        int lb = cur[b] - c;                    // run start in LDS
        int lim = (b + 1) * CAP - gb;           // overflow clamp (statistically never)
        int cc = c < lim ? c : lim;
        for (int k = ln; k < cc; k += 64) part[gb + k] = lsrt[lb + k];
    }
}

// ---------------- per-bucket LDS sort -> node-sorted src list (in place) + CSR + dinv ----------------
__global__ __launch_bounds__(512) void k_sort(unsigned* __restrict__ part, const int* __restrict__ bcur,
                                              int* __restrict__ off, int* __restrict__ off_end,
                                              float* __restrict__ dinv) {
    __shared__ int deg[NB];
    __shared__ int sc[NB];
    __shared__ int offl[NB];
    __shared__ int cur[NB];
    __shared__ int lsort[CAP];  // 36 KB
    int b = blockIdx.x, t = threadIdx.x;
    int e0 = b * CAP;
    int cnt = bcur[b];
    if (cnt > CAP) cnt = CAP;
    for (int i = t; i < NB; i += 512) deg[i] = 0;
    __syncthreads();
    // local degree histogram
    for (int i = t; i < cnt; i += 512) atomicAdd(&deg[part[e0 + i] & (NB - 1)], 1);
    __syncthreads();
    // exclusive scan over 128 local nodes
    if (t < NB) sc[t] = deg[t];
    __syncthreads();
    for (int d = 1; d < NB; d <<= 1) {
        int add = (t < NB && t >= d) ? sc[t - d] : 0;
        __syncthreads();
        if (t < NB) sc[t] += add;
        __syncthreads();
    }
    if (t < NB) { int ex = sc[t] - deg[t]; offl[t] = ex; cur[t] = ex; }
    __syncthreads();
    // scatter srcs into LDS at final rank
    for (int i = t; i < cnt; i += 512) {
        unsigned u = part[e0 + i];
        int r = atomicAdd(&cur[u & (NB - 1)], 1);
        lsort[r] = (int)(u >> 7);
    }
    __syncthreads();
    // coalesced writeback (in place)
    for (int i = t; i < cnt; i += 512) part[e0 + i] = (unsigned)lsort[i];
    // node-level CSR + dinv
    if (t < NB) {
        int n = b * NB + t;
        if (n < N_NODES) {
            off[n] = e0 + offl[t];
            off_end[n] = e0 + offl[t] + deg[t];
            dinv[n] = rsqrtf((float)(deg[t] + 1));  // +1 self loop
        }
    }
}

// ---------------- g1 = fp16( dinv * (x @ W1) ) ----------------
__global__ __launch_bounds__(256) void k_gemm1(const float* __restrict__ x, const float* __restrict__ W1,
                                               const float* __restrict__ dinv, __half* __restrict__ g1) {
    __shared__ float Ws[NF * NH];  // 8 KB
    for (int i = threadIdx.x; i < NF * NH; i += 256) Ws[i] = W1[i];
    __syncthreads();
    int gid = blockIdx.x * 256 + threadIdx.x;
    int n = gid >> 4, j = gid & 15;
    if (n >= N_NODES) return;
    const float4* xr = (const float4*)(x + (size_t)n * NF);
    float acc = 0.f;
    #pragma unroll
    for (int k4 = 0; k4 < NF / 4; k4++) {
        float4 v = xr[k4];
        acc += v.x * Ws[(k4 * 4 + 0) * NH + j];
        acc += v.y * Ws[(k4 * 4 + 1) * NH + j];
        acc += v.z * Ws[(k4 * 4 + 2) * NH + j];
        acc += v.w * Ws[(k4 * 4 + 3) * NH + j];
    }
    g1[(size_t)n * NH + j] = __float2half(dinv[n] * acc);
}

// ---- pull aggregate (R10 champion, unchanged): 1 wave/node, 2 lanes/edge-halfrow,
// 128 edges/iter (4 slots/lane), f16 packed accumulate, bpermute shuffle tree.
// LAYER1: relu + W2 fused (fp16 out, dinv folded).  LAYER2: sigmoid, f32 out.
__device__ __forceinline__ __half2 shx(__half2 x, int m) {
    union { __half2 h; int i; } u;
    u.h = x;
    u.i = __shfl_xor(u.i, m, 64);
    return u.h;
}

template <int LAYER>
__global__ __launch_bounds__(256) void k_agg(const __half* __restrict__ g, const int* __restrict__ off,
                                             const int* __restrict__ off_end,
                                             const unsigned* __restrict__ sorted,
                                             const float* __restrict__ dinv,
                                             const float* __restrict__ bias, const float* __restrict__ W2,
                                             void* __restrict__ outp) {
    __shared__ __align__(16) unsigned redu[4][8];   // [wave][c*4 + word]: raw f16-pair sums
    __shared__ float redf[4][NH];                   // [wave]: relu row (layer 1)
    __shared__ __align__(16) float W2T[16 * 20];    // W2 transposed, +4 pad
    int t = threadIdx.x;
    if (LAYER == 1) {
        int j = t >> 4, k = t & 15;
        W2T[j * 20 + k] = W2[k * 16 + j];           // W2T[j][k] = W2[k][j]
        __syncthreads();
    }
    int w = t >> 6, lane = t & 63;
    int n = blockIdx.x * 4 + w;                     // grid exact: 25000*4 = 100000
    int slot = lane & 31, c = lane >> 5;            // edge slot, 16B half-row selector
    int o0 = off[n], o1 = off_end[n];
    const char* gbase = (const char*)g + (c << 4);

    // hoisted: self row + dinv (overlap with gather loop)
    int j = lane & 15;
    float dn = dinv[n];
    float selfj = __half2float(g[(size_t)n * NH + j]);

    union HV { uint4 q; __half2 h[4]; };
    __half2 a0 = __half2(0.f, 0.f), a1 = a0, a2 = a0, a3 = a0;
    for (int eb = o0; eb < o1; eb += 128) {
        int e1 = eb + slot, e2 = e1 + 32, e3 = e1 + 64, e4 = e1 + 96;
        HV v1, v2, v3, v4;
        v1.q = make_uint4(0u, 0u, 0u, 0u);
        v2.q = make_uint4(0u, 0u, 0u, 0u);
        v3.q = make_uint4(0u, 0u, 0u, 0u);
        v4.q = make_uint4(0u, 0u, 0u, 0u);
        if (e1 < o1) {
            unsigned s = sorted[e1];
            v1.q = *(const uint4*)(gbase + ((size_t)s << 5));
        }
        if (e2 < o1) {
            unsigned s = sorted[e2];
            v2.q = *(const uint4*)(gbase + ((size_t)s << 5));
        }
        if (e3 < o1) {
            unsigned s = sorted[e3];
            v3.q = *(const uint4*)(gbase + ((size_t)s << 5));
        }
        if (e4 < o1) {
            unsigned s = sorted[e4];
            v4.q = *(const uint4*)(gbase + ((size_t)s << 5));
        }
        a0 = __hadd2(a0, __hadd2(__hadd2(v1.h[0], v2.h[0]), __hadd2(v3.h[0], v4.h[0])));
        a1 = __hadd2(a1, __hadd2(__hadd2(v1.h[1], v2.h[1]), __hadd2(v3.h[1], v4.h[1])));
        a2 = __hadd2(a2, __hadd2(__hadd2(v1.h[2], v2.h[2]), __hadd2(v3.h[2], v4.h[2])));
        a3 = __hadd2(a3, __hadd2(__hadd2(v1.h[3], v2.h[3]), __hadd2(v3.h[3], v4.h[3])));
    }
    // 5-stage tree over each 32-lane half (xor masks < 32 keep halves separate)
    #pragma unroll
    for (int m = 1; m <= 16; m <<= 1) {
        a0 = __hadd2(a0, shx(a0, m));
        a1 = __hadd2(a1, shx(a1, m));
        a2 = __hadd2(a2, shx(a2, m));
        a3 = __hadd2(a3, shx(a3, m));
    }
    // lanes 0 and 32 publish raw words (one ds_write_b128 each)
    if (slot == 0) {
        union { uint4 q; __half2 h[4]; } p;
        p.h[0] = a0; p.h[1] = a1; p.h[2] = a2; p.h[3] = a3;
        *(uint4*)&redu[w][c * 4] = p.q;
    }
    // feature j -> half j>>3, word (j&7)>>1, f16 sel j&1   (same-wave LDS RAW: in-order)
    union { unsigned u; __half2 h; } pick;
    pick.u = redu[w][((j >> 3) << 2) + ((j & 7) >> 1)];
    float sumj = __half2float((j & 1) ? __high2half(pick.h) : __low2half(pick.h));
    if (LAYER == 1) {
        if (lane < NH) {
            redf[w][j] = fmaxf(fmaf(dn, sumj + selfj, bias[j]), 0.f);
            float4 r0 = *(const float4*)&redf[w][0];
            float4 r1 = *(const float4*)&redf[w][4];
            float4 r2 = *(const float4*)&redf[w][8];
            float4 r3 = *(const float4*)&redf[w][12];
            const float* wr = &W2T[j * 20];
            float4 w0 = *(const float4*)&wr[0];
            float4 w1 = *(const float4*)&wr[4];
            float4 w2 = *(const float4*)&wr[8];
            float4 w3 = *(const float4*)&wr[12];
            float h = r0.x * w0.x + r0.y * w0.y + r0.z * w0.z + r0.w * w0.w
                    + r1.x * w1.x + r1.y * w1.y + r1.z * w1.z + r1.w * w1.w
                    + r2.x * w2.x + r2.y * w2.y + r2.z * w2.z + r2.w * w2.w
                    + r3.x * w3.x + r3.y * w3.y + r3.z * w3.z + r3.w * w3.w;
            ((__half*)outp)[(size_t)n * NH + j] = __float2half(dn * h);
        }
    } else {
        if (lane < NH) {
            float z = fmaf(dn, sumj + selfj, bias[j]);
            ((float*)outp)[(size_t)n * NH + j] = 1.f / (1.f + __expf(-z));
        }
    }
}

extern "C" void kernel_launch(void* const* d_in, const int* in_sizes, int n_in,
                              void* d_out, int out_size, void* d_ws, size_t ws_size,
                              hipStream_t stream) {
    const float* x  = (const float*)d_in[0];
    const int* eidx = (const int*)d_in[1];
    const float* W1 = (const float*)d_in[2];
    const float* b1 = (const float*)d_in[3];
    const float* W2 = (const float*)d_in[4];
    const float* b2 = (const float*)d_in[5];
    const int* src = eidx;
    const int* dst = eidx + N_EDGES;
    float* out = (float*)d_out;

    char* ws = (char*)d_ws;
    size_t o = 0;
    auto alloc = [&](size_t bytes) { size_t r = o; o = (o + bytes + 255) & ~(size_t)255; return r; };
    int*      bcur    = (int*)     (ws + alloc(sizeof(int) * KB));
    unsigned* part    = (unsigned*)(ws + alloc(sizeof(unsigned) * ((size_t)KB * CAP + 512)));  // +pad
    int*      off     = (int*)     (ws + alloc(sizeof(int) * N_NODES));
    int*      off_end = (int*)     (ws + alloc(sizeof(int) * N_NODES));
    float*    dinv    = (float*)   (ws + alloc(sizeof(float) * N_NODES));
    __half*   g1      = (__half*)  (ws + alloc(sizeof(__half) * N_NODES * NH));
    __half*   g2      = (__half*)  (ws + alloc(sizeof(__half) * N_NODES * NH));
    (void)ws_size; (void)n_in; (void)in_sizes; (void)out_size;

    hipMemsetAsync(bcur, 0, sizeof(int) * KB, stream);

    k_part<<<PT_BLOCKS, PT_THREADS, 0, stream>>>(src, dst, bcur, part);
    k_sort<<<KB, 512, 0, stream>>>(part, bcur, off, off_end, dinv);

    k_gemm1<<<(N_NODES * NH + 255) / 256, 256, 0, stream>>>(x, W1, dinv, g1);

    k_agg<1><<<N_NODES / 4, 256, 0, stream>>>(g1, off, off_end, part, dinv, b1, W2, g2);
    k_agg<2><<<N_NODES / 4, 256, 0, stream>>>(g2, off, off_end, part, dinv, b2, nullptr, out);
}

// Round 16
// 182.016 us; speedup vs baseline: 1.2674x; 1.0176x over previous
//
#include <hip/hip_runtime.h>
#include <hip/hip_fp16.h>
#include <math.h>

#define N_NODES 100000
#define N_EDGES 6400000
#define NF 128
#define NH 16
#define NB 128                          // nodes per bucket
#define KB 782                          // ceil(100000/128)
#define CAP 9216                        // static bucket capacity (mean 8192, sd ~90)

#define PT_THREADS 1024
#define PT_EPT 16
#define PT_TILE (PT_THREADS * PT_EPT)   // 16384 edges per block (long runs -> low write amp)
#define PT_BLOCKS ((N_EDGES + PT_TILE - 1) / PT_TILE)  // 391
#define PT_WAVES (PT_THREADS / 64)      // 16
#define PT_V4 (PT_EPT / 4)              // 4 dwordx4 loads per lane per pass

#define ST_EPT (CAP / 512)              // 18 edges per thread, reg-cached

// ---------------- single-pass partition: LDS multisplit + coalesced burst run writes ----------------
// R15-proven: 1024 threads, 16K tile, wave-shuffle scan (3 barriers), dwordx4 edge loads.
__global__ __launch_bounds__(PT_THREADS) void k_part(const int* __restrict__ src, const int* __restrict__ dst,
                                                     int* __restrict__ bcur, unsigned* __restrict__ part) {
    __shared__ int lcnt[KB];            // per-bucket count in this tile
    __shared__ int lbase[KB];           // global write base (absolute)
    __shared__ int cur[KB];             // LDS scatter cursors
    __shared__ int wsum[PT_WAVES];
    __shared__ int woff[PT_WAVES];
    __shared__ unsigned lsrt[PT_TILE];  // 64 KB tile-sorted packed edges
    int t = threadIdx.x;
    int e0 = blockIdx.x * PT_TILE;
    int d_reg[PT_EPT];

    for (int i = t; i < KB; i += PT_THREADS) lcnt[i] = 0;
    __syncthreads();
    // pass 1: histogram (dwordx4 dst loads, cache in regs)
    #pragma unroll
    for (int r = 0; r < PT_V4; r++) {
        int i = e0 + (r * PT_THREADS + t) * 4;
        if (i + 3 < N_EDGES) {
            int4 d4 = *(const int4*)(dst + i);
            d_reg[r * 4 + 0] = d4.x; d_reg[r * 4 + 1] = d4.y;
            d_reg[r * 4 + 2] = d4.z; d_reg[r * 4 + 3] = d4.w;
            atomicAdd(&lcnt[d4.x >> 7], 1);
            atomicAdd(&lcnt[d4.y >> 7], 1);
            atomicAdd(&lcnt[d4.z >> 7], 1);
            atomicAdd(&lcnt[d4.w >> 7], 1);
        } else {
            #pragma unroll
            for (int k = 0; k < 4; k++) {
                int ii = i + k;
                if (ii < N_EDGES) {
                    int d = dst[ii];
                    d_reg[r * 4 + k] = d;
                    atomicAdd(&lcnt[d >> 7], 1);
                } else d_reg[r * 4 + k] = -1;
            }
        }
    }
    __syncthreads();
    // wave-shuffle exclusive scan of lcnt[0..KB)
    int lane_ = t & 63, wv_ = t >> 6;
    int v = (t < KB) ? lcnt[t] : 0;
    int inc = v;
    #pragma unroll
    for (int d = 1; d < 64; d <<= 1) {
        int u = __shfl_up(inc, d, 64);
        if (lane_ >= d) inc += u;
    }
    if (lane_ == 63) wsum[wv_] = inc;
    __syncthreads();
    if (t < PT_WAVES) {
        int s = 0;
        for (int k = 0; k < t; k++) s += wsum[k];
        woff[t] = s;
    }
    __syncthreads();
    if (t < KB) cur[t] = inc - v + woff[wv_];   // exclusive scan result
    // reserve global run space: one atomic per (block,bucket)
    for (int b = t; b < KB; b += PT_THREADS) {
        int c = lcnt[b];
        lbase[b] = b * CAP + (c ? atomicAdd(&bcur[b], c) : 0);
    }
    __syncthreads();
    // pass 2: rank-scatter packed edges into LDS (dwordx4 src reload)
    #pragma unroll
    for (int r = 0; r < PT_V4; r++) {
        int i = e0 + (r * PT_THREADS + t) * 4;
        if (i + 3 < N_EDGES) {
            int4 s4 = *(const int4*)(src + i);
            int d0 = d_reg[r * 4 + 0], d1 = d_reg[r * 4 + 1];
            int d2 = d_reg[r * 4 + 2], d3 = d_reg[r * 4 + 3];
            int p0 = atomicAdd(&cur[d0 >> 7], 1);
            lsrt[p0] = ((unsigned)s4.x << 7) | (unsigned)(d0 & (NB - 1));
            int p1 = atomicAdd(&cur[d1 >> 7], 1);
            lsrt[p1] = ((unsigned)s4.y << 7) | (unsigned)(d1 & (NB - 1));
            int p2 = atomicAdd(&cur[d2 >> 7], 1);
            lsrt[p2] = ((unsigned)s4.z << 7) | (unsigned)(d2 & (NB - 1));
            int p3 = atomicAdd(&cur[d3 >> 7], 1);
            lsrt[p3] = ((unsigned)s4.w << 7) | (unsigned)(d3 & (NB - 1));
        } else {
            #pragma unroll
            for (int k = 0; k < 4; k++) {
                int d = d_reg[r * 4 + k];
                if (d >= 0) {
                    int ii = i + k;
                    int p = atomicAdd(&cur[d >> 7], 1);
                    lsrt[p] = ((unsigned)src[ii] << 7) | (unsigned)(d & (NB - 1));
                }
            }
        }
    }
    __syncthreads();
    // pass 3: burst writeback, one wave per bucket-run, lanes coalesced
    int wv = t >> 6, ln = t & 63;
    for (int b = wv; b < KB; b += PT_WAVES) {
        int c = lcnt[b];
        if (!c) continue;
        int gb = lbase[b];
        int lb = cur[b] - c;                    // run start in LDS
        int lim = (b + 1) * CAP - gb;           // overflow clamp (statistically never)
        int cc = c < lim ? c : lim;
        for (int k = ln; k < cc; k += 64) part[gb + k] = lsrt[lb + k];
    }
}

// ---------------- per-bucket LDS sort -> node-sorted src list (in place) + CSR + dinv ----------------
// R16: edges reg-cached (single global read pass), 2-wave shuffle scan (6 barriers, was ~17).
__global__ __launch_bounds__(512) void k_sort(unsigned* __restrict__ part, const int* __restrict__ bcur,
                                              int* __restrict__ off, int* __restrict__ off_end,
                                              float* __restrict__ dinv) {
    __shared__ int deg[NB];
    __shared__ int offl[NB];
    __shared__ int cur[NB];
    __shared__ int wtot;        // wave-0 scan total
    __shared__ int lsort[CAP];  // 36 KB
    int b = blockIdx.x, t = threadIdx.x;
    int e0 = b * CAP;
    int cnt = bcur[b];
    if (cnt > CAP) cnt = CAP;
    unsigned ereg[ST_EPT];      // 18 edges cached in VGPRs

    for (int i = t; i < NB; i += 512) deg[i] = 0;
    __syncthreads();
    // single read pass: cache + histogram
    #pragma unroll
    for (int r = 0; r < ST_EPT; r++) {
        int i = r * 512 + t;
        if (i < cnt) {
            unsigned u = part[e0 + i];
            ereg[r] = u;
            atomicAdd(&deg[u & (NB - 1)], 1);
        }
    }
    __syncthreads();
    // 2-wave shuffle exclusive scan over 128 local nodes
    int lane = t & 63;
    int v = (t < NB) ? deg[t] : 0;
    int inc = v;
    #pragma unroll
    for (int d = 1; d < 64; d <<= 1) {
        int u = __shfl_up(inc, d, 64);
        if (lane >= d) inc += u;
    }
    if (t == 63) wtot = inc;
    __syncthreads();
    if (t < NB) {
        int ex = inc - v + ((t >= 64) ? wtot : 0);
        offl[t] = ex;
        cur[t] = ex;
    }
    __syncthreads();
    // scatter srcs into LDS at final rank (from regs)
    #pragma unroll
    for (int r = 0; r < ST_EPT; r++) {
        int i = r * 512 + t;
        if (i < cnt) {
            unsigned u = ereg[r];
            int rk = atomicAdd(&cur[u & (NB - 1)], 1);
            lsort[rk] = (int)(u >> 7);
        }
    }
    __syncthreads();
    // coalesced writeback (in place)
    for (int i = t; i < cnt; i += 512) part[e0 + i] = (unsigned)lsort[i];
    // node-level CSR + dinv
    if (t < NB) {
        int n = b * NB + t;
        if (n < N_NODES) {
            off[n] = e0 + offl[t];
            off_end[n] = e0 + offl[t] + deg[t];
            dinv[n] = rsqrtf((float)(deg[t] + 1));  // +1 self loop
        }
    }
}

// ---------------- g1 = fp16( dinv * (x @ W1) ) ----------------
__global__ __launch_bounds__(256) void k_gemm1(const float* __restrict__ x, const float* __restrict__ W1,
                                               const float* __restrict__ dinv, __half* __restrict__ g1) {
    __shared__ float Ws[NF * NH];  // 8 KB
    for (int i = threadIdx.x; i < NF * NH; i += 256) Ws[i] = W1[i];
    __syncthreads();
    int gid = blockIdx.x * 256 + threadIdx.x;
    int n = gid >> 4, j = gid & 15;
    if (n >= N_NODES) return;
    const float4* xr = (const float4*)(x + (size_t)n * NF);
    float acc = 0.f;
    #pragma unroll
    for (int k4 = 0; k4 < NF / 4; k4++) {
        float4 v = xr[k4];
        acc += v.x * Ws[(k4 * 4 + 0) * NH + j];
        acc += v.y * Ws[(k4 * 4 + 1) * NH + j];
        acc += v.z * Ws[(k4 * 4 + 2) * NH + j];
        acc += v.w * Ws[(k4 * 4 + 3) * NH + j];
    }
    g1[(size_t)n * NH + j] = __float2half(dinv[n] * acc);
}

// ---- pull aggregate (champion, unchanged): 1 wave/node, 2 lanes/edge-halfrow,
// 128 edges/iter (4 slots/lane), f16 packed accumulate, bpermute shuffle tree.
// LAYER1: relu + W2 fused (fp16 out, dinv folded).  LAYER2: sigmoid, f32 out.
__device__ __forceinline__ __half2 shx(__half2 x, int m) {
    union { __half2 h; int i; } u;
    u.h = x;
    u.i = __shfl_xor(u.i, m, 64);
    return u.h;
}

template <int LAYER>
__global__ __launch_bounds__(256) void k_agg(const __half* __restrict__ g, const int* __restrict__ off,
                                             const int* __restrict__ off_end,
                                             const unsigned* __restrict__ sorted,
                                             const float* __restrict__ dinv,
                                             const float* __restrict__ bias, const float* __restrict__ W2,
                                             void* __restrict__ outp) {
    __shared__ __align__(16) unsigned redu[4][8];   // [wave][c*4 + word]: raw f16-pair sums
    __shared__ float redf[4][NH];                   // [wave]: relu row (layer 1)
    __shared__ __align__(16) float W2T[16 * 20];    // W2 transposed, +4 pad
    int t = threadIdx.x;
    if (LAYER == 1) {
        int j = t >> 4, k = t & 15;
        W2T[j * 20 + k] = W2[k * 16 + j];           // W2T[j][k] = W2[k][j]
        __syncthreads();
    }
    int w = t >> 6, lane = t & 63;
    int n = blockIdx.x * 4 + w;                     // grid exact: 25000*4 = 100000
    int slot = lane & 31, c = lane >> 5;            // edge slot, 16B half-row selector
    int o0 = off[n], o1 = off_end[n];
    const char* gbase = (const char*)g + (c << 4);

    // hoisted: self row + dinv (overlap with gather loop)
    int j = lane & 15;
    float dn = dinv[n];
    float selfj = __half2float(g[(size_t)n * NH + j]);

    union HV { uint4 q; __half2 h[4]; };
    __half2 a0 = __half2(0.f, 0.f), a1 = a0, a2 = a0, a3 = a0;
    for (int eb = o0; eb < o1; eb += 128) {
        int e1 = eb + slot, e2 = e1 + 32, e3 = e1 + 64, e4 = e1 + 96;
        HV v1, v2, v3, v4;
        v1.q = make_uint4(0u, 0u, 0u, 0u);
        v2.q = make_uint4(0u, 0u, 0u, 0u);
        v3.q = make_uint4(0u, 0u, 0u, 0u);
        v4.q = make_uint4(0u, 0u, 0u, 0u);
        if (e1 < o1) {
            unsigned s = sorted[e1];
            v1.q = *(const uint4*)(gbase + ((size_t)s << 5));
        }
        if (e2 < o1) {
            unsigned s = sorted[e2];
            v2.q = *(const uint4*)(gbase + ((size_t)s << 5));
        }
        if (e3 < o1) {
            unsigned s = sorted[e3];
            v3.q = *(const uint4*)(gbase + ((size_t)s << 5));
        }
        if (e4 < o1) {
            unsigned s = sorted[e4];
            v4.q = *(const uint4*)(gbase + ((size_t)s << 5));
        }
        a0 = __hadd2(a0, __hadd2(__hadd2(v1.h[0], v2.h[0]), __hadd2(v3.h[0], v4.h[0])));
        a1 = __hadd2(a1, __hadd2(__hadd2(v1.h[1], v2.h[1]), __hadd2(v3.h[1], v4.h[1])));
        a2 = __hadd2(a2, __hadd2(__hadd2(v1.h[2], v2.h[2]), __hadd2(v3.h[2], v4.h[2])));
        a3 = __hadd2(a3, __hadd2(__hadd2(v1.h[3], v2.h[3]), __hadd2(v3.h[3], v4.h[3])));
    }
    // 5-stage tree over each 32-lane half (xor masks < 32 keep halves separate)
    #pragma unroll
    for (int m = 1; m <= 16; m <<= 1) {
        a0 = __hadd2(a0, shx(a0, m));
        a1 = __hadd2(a1, shx(a1, m));
        a2 = __hadd2(a2, shx(a2, m));
        a3 = __hadd2(a3, shx(a3, m));
    }
    // lanes 0 and 32 publish raw words (one ds_write_b128 each)
    if (slot == 0) {
        union { uint4 q; __half2 h[4]; } p;
        p.h[0] = a0; p.h[1] = a1; p.h[2] = a2; p.h[3] = a3;
        *(uint4*)&redu[w][c * 4] = p.q;
    }
    // feature j -> half j>>3, word (j&7)>>1, f16 sel j&1   (same-wave LDS RAW: in-order)
    union { unsigned u; __half2 h; } pick;
    pick.u = redu[w][((j >> 3) << 2) + ((j & 7) >> 1)];
    float sumj = __half2float((j & 1) ? __high2half(pick.h) : __low2half(pick.h));
    if (LAYER == 1) {
        if (lane < NH) {
            redf[w][j] = fmaxf(fmaf(dn, sumj + selfj, bias[j]), 0.f);
            float4 r0 = *(const float4*)&redf[w][0];
            float4 r1 = *(const float4*)&redf[w][4];
            float4 r2 = *(const float4*)&redf[w][8];
            float4 r3 = *(const float4*)&redf[w][12];
            const float* wr = &W2T[j * 20];
            float4 w0 = *(const float4*)&wr[0];
            float4 w1 = *(const float4*)&wr[4];
            float4 w2 = *(const float4*)&wr[8];
            float4 w3 = *(const float4*)&wr[12];
            float h = r0.x * w0.x + r0.y * w0.y + r0.z * w0.z + r0.w * w0.w
                    + r1.x * w1.x + r1.y * w1.y + r1.z * w1.z + r1.w * w1.w
                    + r2.x * w2.x + r2.y * w2.y + r2.z * w2.z + r2.w * w2.w
                    + r3.x * w3.x + r3.y * w3.y + r3.z * w3.z + r3.w * w3.w;
            ((__half*)outp)[(size_t)n * NH + j] = __float2half(dn * h);
        }
    } else {
        if (lane < NH) {
            float z = fmaf(dn, sumj + selfj, bias[j]);
            ((float*)outp)[(size_t)n * NH + j] = 1.f / (1.f + __expf(-z));
        }
    }
}

extern "C" void kernel_launch(void* const* d_in, const int* in_sizes, int n_in,
                              void* d_out, int out_size, void* d_ws, size_t ws_size,
                              hipStream_t stream) {
    const float* x  = (const float*)d_in[0];
    const int* eidx = (const int*)d_in[1];
    const float* W1 = (const float*)d_in[2];
    const float* b1 = (const float*)d_in[3];
    const float* W2 = (const float*)d_in[4];
    const float* b2 = (const float*)d_in[5];
    const int* src = eidx;
    const int* dst = eidx + N_EDGES;
    float* out = (float*)d_out;

    char* ws = (char*)d_ws;
    size_t o = 0;
    auto alloc = [&](size_t bytes) { size_t r = o; o = (o + bytes + 255) & ~(size_t)255; return r; };
    int*      bcur    = (int*)     (ws + alloc(sizeof(int) * KB));
    unsigned* part    = (unsigned*)(ws + alloc(sizeof(unsigned) * ((size_t)KB * CAP + 512)));  // +pad
    int*      off     = (int*)     (ws + alloc(sizeof(int) * N_NODES));
    int*      off_end = (int*)     (ws + alloc(sizeof(int) * N_NODES));
    float*    dinv    = (float*)   (ws + alloc(sizeof(float) * N_NODES));
    __half*   g1      = (__half*)  (ws + alloc(sizeof(__half) * N_NODES * NH));
    __half*   g2      = (__half*)  (ws + alloc(sizeof(__half) * N_NODES * NH));
    (void)ws_size; (void)n_in; (void)in_sizes; (void)out_size;

    hipMemsetAsync(bcur, 0, sizeof(int) * KB, stream);

    k_part<<<PT_BLOCKS, PT_THREADS, 0, stream>>>(src, dst, bcur, part);
    k_sort<<<KB, 512, 0, stream>>>(part, bcur, off, off_end, dinv);

    k_gemm1<<<(N_NODES * NH + 255) / 256, 256, 0, stream>>>(x, W1, dinv, g1);

    k_agg<1><<<N_NODES / 4, 256, 0, stream>>>(g1, off, off_end, part, dinv, b1, W2, g2);
    k_agg<2><<<N_NODES / 4, 256, 0, stream>>>(g2, off, off_end, part, dinv, b2, nullptr, out);
}